// Round 7
// baseline (9567.453 us; speedup 1.0000x reference)
//
#include <hip/hip_runtime.h>
#include <stdint.h>

#define TT 2048
#define BB 8
#define II 512
#define HH 512
#define GG 32           // workgroups per direction
#define HS 16           // hidden units per WG
#define SLOT (BB*HH)    // 4096 bf16 elems per h-history slot

typedef __attribute__((ext_vector_type(8))) short short8;
typedef __attribute__((ext_vector_type(4))) float float4v;
typedef __attribute__((ext_vector_type(2))) float floatx2;
typedef __attribute__((ext_vector_type(2))) unsigned long long ull2;

__device__ __forceinline__ unsigned short f2bf(float f) {
  unsigned u = __builtin_bit_cast(unsigned, f);
  u = u + 0x7FFFu + ((u >> 16) & 1u);   // RNE
  return (unsigned short)(u >> 16);
}

__device__ __forceinline__ float fsigmoid(float x) {
  return __fdividef(1.0f, 1.0f + __expf(-x));
}
__device__ __forceinline__ float ftanh(float x) {
  float e = __expf(-2.0f * fabsf(x));   // in (0,1], never overflows
  float r = __fdividef(1.0f - e, 1.0f + e);
  return x < 0.0f ? -r : r;
}

// input[b][t][k] fp32  ->  xbf[t][b][k] bf16
__global__ void xprep_kernel(const float* __restrict__ x,
                             unsigned short* __restrict__ xbf) {
  int idx = blockIdx.x * 256 + threadIdx.x;   // 1,048,576 threads, 8 elems each
  int k8 = idx & 63;
  int bt = idx >> 6;
  int t  = bt & (TT - 1);
  int b  = bt >> 11;
  const float* src = x + ((size_t)b * TT + t) * II + (size_t)k8 * 8;
  float4v v0 = *(const float4v*)src;
  float4v v1 = *(const float4v*)(src + 4);
  short8 o;
  o[0] = (short)f2bf(v0[0]); o[1] = (short)f2bf(v0[1]);
  o[2] = (short)f2bf(v0[2]); o[3] = (short)f2bf(v0[3]);
  o[4] = (short)f2bf(v1[0]); o[5] = (short)f2bf(v1[1]);
  o[6] = (short)f2bf(v1[2]); o[7] = (short)f2bf(v1[3]);
  *(short8*)(xbf + ((size_t)t * BB + b) * II + (size_t)k8 * 8) = o;
}

// Round-0 substrate (agent/MALL sync, grid 64, NO XCD assumptions — proven
// green) with a restructured critical path:
//  - wave0-only epilogue: all 128 cells (2/lane), packed dword h-stores;
//    one in-wave vmcnt(0) then the flag. Second barrier DELETED.
//  - lds_g reuse is ordered by the flag protocol itself (step s+1 lds writes
//    happen only after all step-s flags, which follow wave0's lds_g reads).
//  - out HBM stores issued AFTER the flag: their ack drains during the next
//    poll, off the recurrence chain.
__global__ __launch_bounds__(256, 1) void lstm_kernel(
    const float* __restrict__ Wih_f, const float* __restrict__ Whh_f,
    const float* __restrict__ bih_f, const float* __restrict__ bhh_f,
    const float* __restrict__ Wih_b, const float* __restrict__ Whh_b,
    const float* __restrict__ bih_b, const float* __restrict__ bhh_b,
    const unsigned short* __restrict__ xbf,
    unsigned short* __restrict__ h_hist,
    int* __restrict__ flags,
    float* __restrict__ out)
{
  const int dir  = blockIdx.x >> 5;
  const int wg   = blockIdx.x & 31;
  const int tid  = threadIdx.x;
  const int wave = tid >> 6;          // gate type: 0=i 1=f 2=g 3=o
  const int lane = tid & 63;
  const int m    = lane & 15;         // A-row within tile / B-col (batch)
  const int q    = lane >> 4;         // quad
  const bool nv  = (m < BB);          // batch lane valid

  const float* __restrict__ Wih = dir ? Wih_b : Wih_f;
  const float* __restrict__ Whh = dir ? Whh_b : Whh_f;
  const float* __restrict__ bih = dir ? bih_b : bih_f;
  const float* __restrict__ bhh = dir ? bhh_b : bhh_f;

  const int j0   = wg * HS;                 // hidden slice [j0, j0+16)
  const int grow = wave * HH + j0 + m;      // gate row this lane loads (A[m][k])

  // ---- persistent weight A-fragments (A[m=lane&15][k=q*8+j]) ----
  short8 a_x[16], a_h[16];
#pragma unroll
  for (int kf = 0; kf < 16; ++kf) {
    const float* p1 = Wih + (size_t)grow * II + kf * 32 + q * 8;
    const float* p2 = Whh + (size_t)grow * HH + kf * 32 + q * 8;
    short8 A, Bv;
#pragma unroll
    for (int j = 0; j < 8; ++j) {
      A[j]  = (short)f2bf(p1[j]);
      Bv[j] = (short)f2bf(p2[j]);
    }
    a_x[kf] = A;
    a_h[kf] = Bv;
  }

  // ---- wave0 epilogue state: 2 cells per lane (jj = ej, ej+1) ----
  const int ebb = lane >> 3;          // batch 0..7
  const int ej  = (lane & 7) * 2;     // even j within slice
  float c0 = 0.0f, c1 = 0.0f;
  float bi0 = 0.f, bf0 = 0.f, bg0 = 0.f, bo0 = 0.f;
  float bi1 = 0.f, bf1 = 0.f, bg1 = 0.f, bo1 = 0.f;
  if (wave == 0) {
    int ja = j0 + ej, jb = ja + 1;
    bi0 = bih[0 * HH + ja] + bhh[0 * HH + ja];
    bf0 = bih[1 * HH + ja] + bhh[1 * HH + ja];
    bg0 = bih[2 * HH + ja] + bhh[2 * HH + ja];
    bo0 = bih[3 * HH + ja] + bhh[3 * HH + ja];
    bi1 = bih[0 * HH + jb] + bhh[0 * HH + jb];
    bf1 = bih[1 * HH + jb] + bhh[1 * HH + jb];
    bg1 = bih[2 * HH + jb] + bhh[2 * HH + jb];
    bo1 = bih[3 * HH + jb] + bhh[3 * HH + jb];
  }

  __shared__ float lds_g[4][16][17];   // [gate][row j][batch], +1 pad

  unsigned short* __restrict__ hh = h_hist + (size_t)dir * (TT + 1) * SLOT;
  int* __restrict__ flg = flags + dir * TT * GG;
  int bailleft = 2000000;   // safety: never hang the harness

#pragma unroll 1
  for (int s = 0; s < TT; ++s) {
    const int t = dir ? (TT - 1 - s) : s;

    float4v acc[4];
#pragma unroll
    for (int i = 0; i < 4; ++i) acc[i] = (float4v){0.f, 0.f, 0.f, 0.f};

    // ---- x contribution: independent of recurrence, overlaps the wait ----
    {
      const unsigned short* xrow =
          xbf + ((size_t)t * BB + (nv ? m : 0)) * II + q * 8;
      short8 bx[16];
#pragma unroll
      for (int kf = 0; kf < 16; ++kf) {
        short8 v = {0, 0, 0, 0, 0, 0, 0, 0};
        if (nv) v = *(const short8*)(xrow + kf * 32);
        bx[kf] = v;
      }
#pragma unroll
      for (int kf = 0; kf < 16; ++kf)
        acc[kf & 3] = __builtin_amdgcn_mfma_f32_16x16x32_bf16(
            a_x[kf], bx[kf], acc[kf & 3], 0, 0, 0);
    }

    // ---- wait for h(s-1) flags from all 32 WGs (each wave independently) ----
    if (s > 0) {
      const int* fl = flg + (size_t)(s - 1) * GG;
      const int fi = lane & 31;
      for (;;) {
        int v = __hip_atomic_load(&fl[fi], __ATOMIC_RELAXED,
                                  __HIP_MEMORY_SCOPE_AGENT);
        if (__ballot(v == 0) == 0ull) break;
        if (--bailleft < 0) break;
      }
      asm volatile("" ::: "memory");   // compile-order: h loads stay below
    }

    // ---- h contribution (agent-scope loads: bypass stale caches) ----
    {
      const unsigned long long* hq = (const unsigned long long*)(
          hh + (size_t)s * SLOT + (size_t)(nv ? m : 0) * HH + q * 8);
      short8 bh[16];
#pragma unroll
      for (int kf = 0; kf < 16; ++kf) {
        ull2 u = {0ull, 0ull};
        if (nv) {
          u[0] = __hip_atomic_load(&hq[kf * 8 + 0], __ATOMIC_RELAXED,
                                   __HIP_MEMORY_SCOPE_AGENT);
          u[1] = __hip_atomic_load(&hq[kf * 8 + 1], __ATOMIC_RELAXED,
                                   __HIP_MEMORY_SCOPE_AGENT);
        }
        bh[kf] = __builtin_bit_cast(short8, u);
      }
#pragma unroll
      for (int kf = 0; kf < 16; ++kf)
        acc[kf & 3] = __builtin_amdgcn_mfma_f32_16x16x32_bf16(
            a_h[kf], bh[kf], acc[kf & 3], 0, 0, 0);
    }

    // ---- gates to LDS (C/D layout: col=lane&15, row=q*4+r) ----
#pragma unroll
    for (int r = 0; r < 4; ++r) {
      float g = acc[0][r] + acc[1][r] + acc[2][r] + acc[3][r];
      lds_g[wave][q * 4 + r][m] = g;
    }
    __syncthreads();   // the ONLY barrier: gates complete before wave0 reads

    // ---- wave0-only epilogue: 2 cells/lane, then h-ack, then flag ----
    if (wave == 0) {
      float gi0 = lds_g[0][ej + 0][ebb] + bi0;
      float gf0 = lds_g[1][ej + 0][ebb] + bf0;
      float gg0 = lds_g[2][ej + 0][ebb] + bg0;
      float go0 = lds_g[3][ej + 0][ebb] + bo0;
      float gi1 = lds_g[0][ej + 1][ebb] + bi1;
      float gf1 = lds_g[1][ej + 1][ebb] + bf1;
      float gg1 = lds_g[2][ej + 1][ebb] + bg1;
      float go1 = lds_g[3][ej + 1][ebb] + bo1;
      c0 = fsigmoid(gf0) * c0 + fsigmoid(gi0) * ftanh(gg0);
      c1 = fsigmoid(gf1) * c1 + fsigmoid(gi1) * ftanh(gg1);
      float hv0 = fsigmoid(go0) * ftanh(c0);
      float hv1 = fsigmoid(go1) * ftanh(c1);
      // publish both h values as ONE dword at agent scope (MALL)
      unsigned pack = (unsigned)f2bf(hv0) | ((unsigned)f2bf(hv1) << 16);
      unsigned* hp = (unsigned*)(hh + (size_t)(s + 1) * SLOT +
                                 (size_t)ebb * HH + j0 + ej);
      __hip_atomic_store(hp, pack, __ATOMIC_RELAXED, __HIP_MEMORY_SCOPE_AGENT);
      // drain THIS wave's stores (covers all 64 lanes' h dwords), then flag
      asm volatile("s_waitcnt vmcnt(0)" ::: "memory");
      if (lane == 0)
        __hip_atomic_store(&flg[(size_t)s * GG + wg], 1, __ATOMIC_RELAXED,
                           __HIP_MEMORY_SCOPE_AGENT);
      // out store AFTER the flag — its HBM ack drains during the next poll
      floatx2 o2 = {hv0, hv1};
      __builtin_nontemporal_store(
          o2, (floatx2*)&out[((size_t)t * BB + ebb) * (2 * HH) +
                             (size_t)dir * HH + j0 + ej]);
    }
    // waves 1-3: no second barrier — straight into step s+1's x-MFMAs.
    // lds_g reuse is safe: any WG's step-s+1 lds writes follow poll(s),
    // which requires OUR flag, which wave0 stores after reading lds_g.
  }
}

extern "C" void kernel_launch(void* const* d_in, const int* in_sizes, int n_in,
                              void* d_out, int out_size, void* d_ws, size_t ws_size,
                              hipStream_t stream) {
  (void)in_sizes; (void)n_in; (void)out_size; (void)ws_size;
  const float* input = (const float*)d_in[0];
  const float* Wih_f = (const float*)d_in[1];
  const float* Whh_f = (const float*)d_in[2];
  const float* bih_f = (const float*)d_in[3];
  const float* bhh_f = (const float*)d_in[4];
  const float* Wih_b = (const float*)d_in[5];
  const float* Whh_b = (const float*)d_in[6];
  const float* bih_b = (const float*)d_in[7];
  const float* bhh_b = (const float*)d_in[8];

  char* ws = (char*)d_ws;
  // layout: [xbf 16,777,216 B][h_hist 33,570,816 B][flags 524,288 B] = 50,872,320
  unsigned short* xbf    = (unsigned short*)(ws);
  unsigned short* h_hist = (unsigned short*)(ws + 16777216);
  int*            flags  = (int*)(ws + 50348032);

  hipMemsetAsync(flags, 0, 2 * TT * GG * sizeof(int), stream);
  hipMemsetAsync(h_hist, 0, SLOT * 2, stream);                                // dir0 h(-1)=0
  hipMemsetAsync((char*)h_hist + (size_t)(TT + 1) * SLOT * 2, 0, SLOT * 2, stream); // dir1

  hipLaunchKernelGGL(xprep_kernel, dim3(4096), dim3(256), 0, stream, input, xbf);
  hipLaunchKernelGGL(lstm_kernel, dim3(64), dim3(256), 0, stream,
                     Wih_f, Whh_f, bih_f, bhh_f, Wih_b, Whh_b, bih_b, bhh_b,
                     xbf, h_hist, flags, (float*)d_out);
}

// Round 8
// 6402.157 us; speedup vs baseline: 1.4944x; 1.4944x over previous
//
#include <hip/hip_runtime.h>
#include <stdint.h>

#define TT 2048
#define BB 8
#define II 512
#define HH 512
#define GG 32           // workgroups per direction
#define HS 16           // hidden units per WG
#define SLOT (BB*HH)    // 4096 bf16 elems per h-history slot
#define SENT32 0x7FC07FC0u   // 2x bf16 qNaN — impossible h value (h = sig*tanh)

typedef __attribute__((ext_vector_type(8))) short short8;
typedef __attribute__((ext_vector_type(4))) float float4v;
typedef __attribute__((ext_vector_type(2))) float floatx2;
typedef __attribute__((ext_vector_type(4))) unsigned uint4v;

__device__ __forceinline__ unsigned short f2bf(float f) {
  unsigned u = __builtin_bit_cast(unsigned, f);
  u = u + 0x7FFFu + ((u >> 16) & 1u);   // RNE
  return (unsigned short)(u >> 16);
}

__device__ __forceinline__ float fsigmoid(float x) {
  return __fdividef(1.0f, 1.0f + __expf(-x));
}
__device__ __forceinline__ float ftanh(float x) {
  float e = __expf(-2.0f * fabsf(x));   // in (0,1], never overflows
  float r = __fdividef(1.0f - e, 1.0f + e);
  return x < 0.0f ? -r : r;
}

// input[b][t][k] fp32  ->  xbf[t][b][k] bf16
__global__ void xprep_kernel(const float* __restrict__ x,
                             unsigned short* __restrict__ xbf) {
  int idx = blockIdx.x * 256 + threadIdx.x;   // 1,048,576 threads, 8 elems each
  int k8 = idx & 63;
  int bt = idx >> 6;
  int t  = bt & (TT - 1);
  int b  = bt >> 11;
  const float* src = x + ((size_t)b * TT + t) * II + (size_t)k8 * 8;
  float4v v0 = *(const float4v*)src;
  float4v v1 = *(const float4v*)(src + 4);
  short8 o;
  o[0] = (short)f2bf(v0[0]); o[1] = (short)f2bf(v0[1]);
  o[2] = (short)f2bf(v0[2]); o[3] = (short)f2bf(v0[3]);
  o[4] = (short)f2bf(v1[0]); o[5] = (short)f2bf(v1[1]);
  o[6] = (short)f2bf(v1[2]); o[7] = (short)f2bf(v1[3]);
  *(short8*)(xbf + ((size_t)t * BB + b) * II + (size_t)k8 * 8) = o;
}

// h_hist init: slot 0 of each dir = 0.0 (h(-1)); slots 1..TT = bf16 qNaN
// sentinel. Stream-ordered before lstm_kernel -> no races by construction.
__global__ void hinit_kernel(unsigned short* __restrict__ hh) {
  size_t e8   = ((size_t)blockIdx.x * 256 + threadIdx.x) * 8;
  size_t slot = (e8 / SLOT) % (TT + 1);
  short v = (slot == 0) ? (short)0 : (short)0x7FC0;
  short8 o = {v, v, v, v, v, v, v, v};
  *(short8*)(hh + e8) = o;
}

// Round-7 substrate (green) with the flag protocol DELETED: consumers poll
// the h-data itself. Every h dword transitions sentinel->final exactly once
// (TT+1 distinct slots, no reuse), so "no dword == SENT32" IS the readiness
// condition — no flags, no store drains, no ordering requirements at all.
__global__ __launch_bounds__(256, 1) void lstm_kernel(
    const float* __restrict__ Wih_f, const float* __restrict__ Whh_f,
    const float* __restrict__ bih_f, const float* __restrict__ bhh_f,
    const float* __restrict__ Wih_b, const float* __restrict__ Whh_b,
    const float* __restrict__ bih_b, const float* __restrict__ bhh_b,
    const unsigned short* __restrict__ xbf,
    unsigned short* __restrict__ h_hist,
    float* __restrict__ out)
{
  const int dir  = blockIdx.x >> 5;
  const int wg   = blockIdx.x & 31;
  const int tid  = threadIdx.x;
  const int wave = tid >> 6;          // gate type: 0=i 1=f 2=g 3=o
  const int lane = tid & 63;
  const int m    = lane & 15;         // A-row within tile / B-col (batch)
  const int q    = lane >> 4;         // quad
  const bool nv  = (m < BB);          // batch lane valid

  const float* __restrict__ Wih = dir ? Wih_b : Wih_f;
  const float* __restrict__ Whh = dir ? Whh_b : Whh_f;
  const float* __restrict__ bih = dir ? bih_b : bih_f;
  const float* __restrict__ bhh = dir ? bhh_b : bhh_f;

  const int j0   = wg * HS;                 // hidden slice [j0, j0+16)
  const int grow = wave * HH + j0 + m;      // gate row this lane loads (A[m][k])

  // ---- persistent weight A-fragments (A[m=lane&15][k=q*8+j]) ----
  short8 a_x[16], a_h[16];
#pragma unroll
  for (int kf = 0; kf < 16; ++kf) {
    const float* p1 = Wih + (size_t)grow * II + kf * 32 + q * 8;
    const float* p2 = Whh + (size_t)grow * HH + kf * 32 + q * 8;
    short8 A, Bv;
#pragma unroll
    for (int j = 0; j < 8; ++j) {
      A[j]  = (short)f2bf(p1[j]);
      Bv[j] = (short)f2bf(p2[j]);
    }
    a_x[kf] = A;
    a_h[kf] = Bv;
  }

  // ---- wave0 epilogue state: 2 cells per lane (jj = ej, ej+1) ----
  const int ebb = lane >> 3;          // batch 0..7
  const int ej  = (lane & 7) * 2;     // even j within slice
  float c0 = 0.0f, c1 = 0.0f;
  float bi0 = 0.f, bf0 = 0.f, bg0 = 0.f, bo0 = 0.f;
  float bi1 = 0.f, bf1 = 0.f, bg1 = 0.f, bo1 = 0.f;
  if (wave == 0) {
    int ja = j0 + ej, jb = ja + 1;
    bi0 = bih[0 * HH + ja] + bhh[0 * HH + ja];
    bf0 = bih[1 * HH + ja] + bhh[1 * HH + ja];
    bg0 = bih[2 * HH + ja] + bhh[2 * HH + ja];
    bo0 = bih[3 * HH + ja] + bhh[3 * HH + ja];
    bi1 = bih[0 * HH + jb] + bhh[0 * HH + jb];
    bf1 = bih[1 * HH + jb] + bhh[1 * HH + jb];
    bg1 = bih[2 * HH + jb] + bhh[2 * HH + jb];
    bo1 = bih[3 * HH + jb] + bhh[3 * HH + jb];
  }

  __shared__ float lds_g[4][16][17];   // [gate][row j][batch], +1 pad

  unsigned short* __restrict__ hh = h_hist + (size_t)dir * (TT + 1) * SLOT;
  int bailleft = 2000000;   // safety: never hang the harness

#pragma unroll 1
  for (int s = 0; s < TT; ++s) {
    const int t = dir ? (TT - 1 - s) : s;

    float4v acc[4];
#pragma unroll
    for (int i = 0; i < 4; ++i) acc[i] = (float4v){0.f, 0.f, 0.f, 0.f};

    // ---- x contribution: independent of recurrence, overlaps the wait ----
    {
      const unsigned short* xrow =
          xbf + ((size_t)t * BB + (nv ? m : 0)) * II + q * 8;
      short8 bx[16];
#pragma unroll
      for (int kf = 0; kf < 16; ++kf) {
        short8 v = {0, 0, 0, 0, 0, 0, 0, 0};
        if (nv) v = *(const short8*)(xrow + kf * 32);
        bx[kf] = v;
      }
#pragma unroll
      for (int kf = 0; kf < 16; ++kf)
        acc[kf & 3] = __builtin_amdgcn_mfma_f32_16x16x32_bf16(
            a_x[kf], bx[kf], acc[kf & 3], 0, 0, 0);
    }

    // ---- h(s-1): poll-on-data. Reload the 16 B-fragments (MALL-coherent,
    //      sc0 sc1 = bypass L1+L2) until no dword holds the sentinel. The
    //      poll IS the load: detect -> fragments already in registers. ----
    short8 bh[16];
    {
      const unsigned short* hrow =
          hh + (size_t)s * SLOT + (size_t)(nv ? m : 0) * HH + q * 8;
      for (;;) {
#pragma unroll
        for (int kf = 0; kf < 16; ++kf)
          asm volatile("global_load_dwordx4 %0, %1, off sc0 sc1"
                       : "=&v"(bh[kf]) : "v"(hrow + kf * 32) : "memory");
        asm volatile("s_waitcnt vmcnt(0)" ::: "memory");
        unsigned bad = 0u;
#pragma unroll
        for (int kf = 0; kf < 16; ++kf) {
          uint4v u = __builtin_bit_cast(uint4v, bh[kf]);
          bad |= (unsigned)(u[0] == SENT32) | (unsigned)(u[1] == SENT32) |
                 (unsigned)(u[2] == SENT32) | (unsigned)(u[3] == SENT32);
        }
        if (__ballot(bad != 0u) == 0ull) break;
        if (--bailleft < 0) break;
      }
    }
    __builtin_amdgcn_sched_barrier(0);   // rule #18: keep MFMAs below the wait

    // ---- U*h (lanes m>=8 hold row-0 data; their output cols never read) ----
#pragma unroll
    for (int kf = 0; kf < 16; ++kf)
      acc[kf & 3] = __builtin_amdgcn_mfma_f32_16x16x32_bf16(
          a_h[kf], bh[kf], acc[kf & 3], 0, 0, 0);

    // ---- gates to LDS (C/D layout: col=lane&15, row=q*4+r) ----
#pragma unroll
    for (int r = 0; r < 4; ++r) {
      float g = acc[0][r] + acc[1][r] + acc[2][r] + acc[3][r];
      lds_g[wave][q * 4 + r][m] = g;
    }
    __syncthreads();   // the ONLY barrier: gates complete before wave0 reads

    // ---- wave0-only epilogue: 2 cells/lane; publish h; NO drain, NO flag ----
    if (wave == 0) {
      float gi0 = lds_g[0][ej + 0][ebb] + bi0;
      float gf0 = lds_g[1][ej + 0][ebb] + bf0;
      float gg0 = lds_g[2][ej + 0][ebb] + bg0;
      float go0 = lds_g[3][ej + 0][ebb] + bo0;
      float gi1 = lds_g[0][ej + 1][ebb] + bi1;
      float gf1 = lds_g[1][ej + 1][ebb] + bf1;
      float gg1 = lds_g[2][ej + 1][ebb] + bg1;
      float go1 = lds_g[3][ej + 1][ebb] + bo1;
      c0 = fsigmoid(gf0) * c0 + fsigmoid(gi0) * ftanh(gg0);
      c1 = fsigmoid(gf1) * c1 + fsigmoid(gi1) * ftanh(gg1);
      float hv0 = fsigmoid(go0) * ftanh(c0);
      float hv1 = fsigmoid(go1) * ftanh(c1);
      // one dword = 2 bf16 cells; sentinel->final transition is atomic (4B)
      unsigned pack = (unsigned)f2bf(hv0) | ((unsigned)f2bf(hv1) << 16);
      unsigned* hp = (unsigned*)(hh + (size_t)(s + 1) * SLOT +
                                 (size_t)ebb * HH + j0 + ej);
      __hip_atomic_store(hp, pack, __ATOMIC_RELAXED, __HIP_MEMORY_SCOPE_AGENT);
      // out store: HBM ack drains under the next step's poll
      floatx2 o2 = {hv0, hv1};
      __builtin_nontemporal_store(
          o2, (floatx2*)&out[((size_t)t * BB + ebb) * (2 * HH) +
                             (size_t)dir * HH + j0 + ej]);
    }
    // waves 1-3: straight into step s+1. lds_g reuse is safe: their step-s+1
    // lds writes follow their poll of h(s+1), which includes OUR wave0's
    // h(s+1) stores, issued only after wave0 finished reading lds_g(s).
  }
}

extern "C" void kernel_launch(void* const* d_in, const int* in_sizes, int n_in,
                              void* d_out, int out_size, void* d_ws, size_t ws_size,
                              hipStream_t stream) {
  (void)in_sizes; (void)n_in; (void)out_size; (void)ws_size;
  const float* input = (const float*)d_in[0];
  const float* Wih_f = (const float*)d_in[1];
  const float* Whh_f = (const float*)d_in[2];
  const float* bih_f = (const float*)d_in[3];
  const float* bhh_f = (const float*)d_in[4];
  const float* Wih_b = (const float*)d_in[5];
  const float* Whh_b = (const float*)d_in[6];
  const float* bih_b = (const float*)d_in[7];
  const float* bhh_b = (const float*)d_in[8];

  char* ws = (char*)d_ws;
  // layout: [xbf 16,777,216 B][h_hist 33,570,816 B] = 50,348,032 (< proven cap)
  unsigned short* xbf    = (unsigned short*)(ws);
  unsigned short* h_hist = (unsigned short*)(ws + 16777216);

  // h_hist: 2*(TT+1)*SLOT = 16,785,408 shorts = 8196 blocks * 256 thr * 8
  hipLaunchKernelGGL(hinit_kernel, dim3(8196), dim3(256), 0, stream, h_hist);
  hipLaunchKernelGGL(xprep_kernel, dim3(4096), dim3(256), 0, stream, input, xbf);
  hipLaunchKernelGGL(lstm_kernel, dim3(64), dim3(256), 0, stream,
                     Wih_f, Whh_f, bih_f, bhh_f, Wih_b, Whh_b, bih_b, bhh_b,
                     xbf, h_hist, (float*)d_out);
}